// Round 2
// baseline (407.719 us; speedup 1.0000x reference)
//
#include <hip/hip_runtime.h>
#include <cstddef>

#define BATCH 8
#define NQ 16384
#define NK 16384
#define FEAT 128
#define MID 16
#define CTXD 128
#define OUTD 128
#define EPSV 1e-5f

#define ROWS 64          // rows per block slab
#define LPAD 132         // f32 LDS row stride (16B-aligned, good banks)

// ws layout (floats):
//   U     [BATCH][MID][OUTD... CTXD]: offset 0      (16384)
//   sumw  [BATCH][MID]        : offset 16384  (128)
//   st    [2][MID]            : offset 16512  (32)
//   lam   [BATCH][MID][OUTD]  : offset 16544  (16384)

__device__ __forceinline__ float readlane_f(float v, int lane) {
    return __uint_as_float(__builtin_amdgcn_readlane(__float_as_uint(v), lane));
}

// ---------------------------------------------------------------------------
// Phase 1: slab of 64 ctx rows. Stage->LDS coalesced; key=ctx@Wk (Wk via
// s_load, uniform group); w=exp(key) kept in regs; U += w^T@ctx via readlane
// broadcast; global f32 atomics.
// ---------------------------------------------------------------------------
__global__ __launch_bounds__(256) void k_phase1(
    const float* __restrict__ ctx, const float* __restrict__ Wk,
    float* __restrict__ U, float* __restrict__ sumw)
{
    __shared__ float cL[ROWS * LPAD];   // 33792 B
    const int b  = blockIdx.y;
    const int r0 = blockIdx.x * ROWS;
    const int t  = threadIdx.x;
    const int lane = t & 63;

    // ---- stage: 64 rows x 128 f32, coalesced float4 ----
    {
        const float4* g4 = (const float4*)(ctx + ((size_t)b * NK + r0) * CTXD);
        float4* c4p = (float4*)cL;
        #pragma unroll
        for (int i = 0; i < 8; ++i) {
            int idx = t + 256 * i;          // 0..2047
            int row = idx >> 5;
            int c4  = idx & 31;
            c4p[row * (LPAD / 4) + c4] = g4[idx];
        }
    }
    __syncthreads();

    // ---- key phase: thread (n=t&63, g=wave id) -> key[4], w[4] in regs ----
    const int g = __builtin_amdgcn_readfirstlane(t >> 6);   // 0..3, SGPR
    float k0 = 0.f, k1 = 0.f, k2 = 0.f, k3 = 0.f;
    {
        const float4* cr = (const float4*)cL + lane * (LPAD / 4);
        const float* wkb = Wk + 4 * g;                      // uniform base
        #pragma unroll 8
        for (int kq = 0; kq < 32; ++kq) {
            float4 c4 = cr[kq];
            const float* w0p = wkb + (4 * kq + 0) * MID;
            const float* w1p = wkb + (4 * kq + 1) * MID;
            const float* w2p = wkb + (4 * kq + 2) * MID;
            const float* w3p = wkb + (4 * kq + 3) * MID;
            k0 += c4.x * w0p[0]; k1 += c4.x * w0p[1]; k2 += c4.x * w0p[2]; k3 += c4.x * w0p[3];
            k0 += c4.y * w1p[0]; k1 += c4.y * w1p[1]; k2 += c4.y * w1p[2]; k3 += c4.y * w1p[3];
            k0 += c4.z * w2p[0]; k1 += c4.z * w2p[1]; k2 += c4.z * w2p[2]; k3 += c4.z * w2p[3];
            k0 += c4.w * w3p[0]; k1 += c4.w * w3p[1]; k2 += c4.w * w3p[2]; k3 += c4.w * w3p[3];
        }
    }
    float w0 = __expf(k0), w1 = __expf(k1), w2 = __expf(k2), w3 = __expf(k3);

    // ---- sumw: wave reduce (all lanes same g) ----
    {
        float s0 = w0, s1 = w1, s2 = w2, s3 = w3;
        #pragma unroll
        for (int off = 32; off > 0; off >>= 1) {
            s0 += __shfl_xor(s0, off);
            s1 += __shfl_xor(s1, off);
            s2 += __shfl_xor(s2, off);
            s3 += __shfl_xor(s3, off);
        }
        if (lane == 0) {
            atomicAdd(&sumw[b * MID + 4 * g + 0], s0);
            atomicAdd(&sumw[b * MID + 4 * g + 1], s1);
            atomicAdd(&sumw[b * MID + 4 * g + 2], s2);
            atomicAdd(&sumw[b * MID + 4 * g + 3], s3);
        }
    }

    // ---- U phase: wave g owns mids 4g..4g+3; lane owns 2 d-columns ----
    float a00 = 0.f, a01 = 0.f, a10 = 0.f, a11 = 0.f;
    float a20 = 0.f, a21 = 0.f, a30 = 0.f, a31 = 0.f;
    #pragma unroll 4
    for (int n2 = 0; n2 < ROWS; ++n2) {
        float b0 = readlane_f(w0, n2);
        float b1 = readlane_f(w1, n2);
        float b2 = readlane_f(w2, n2);
        float b3 = readlane_f(w3, n2);
        float2 c2 = *(const float2*)(cL + n2 * LPAD + 2 * lane);
        a00 += b0 * c2.x; a01 += b0 * c2.y;
        a10 += b1 * c2.x; a11 += b1 * c2.y;
        a20 += b2 * c2.x; a21 += b2 * c2.y;
        a30 += b3 * c2.x; a31 += b3 * c2.y;
    }
    {
        float* u0 = U + ((size_t)b * MID + 4 * g + 0) * CTXD + 2 * lane;
        float* u1 = U + ((size_t)b * MID + 4 * g + 1) * CTXD + 2 * lane;
        float* u2 = U + ((size_t)b * MID + 4 * g + 2) * CTXD + 2 * lane;
        float* u3 = U + ((size_t)b * MID + 4 * g + 3) * CTXD + 2 * lane;
        atomicAdd(u0, a00); atomicAdd(u0 + 1, a01);
        atomicAdd(u1, a10); atomicAdd(u1 + 1, a11);
        atomicAdd(u2, a20); atomicAdd(u2 + 1, a21);
        atomicAdd(u3, a30); atomicAdd(u3 + 1, a31);
    }
}

// ---------------------------------------------------------------------------
// Phase 2: lam = (U@Wv)/sumw + BN stats (unchanged from round 1)
// ---------------------------------------------------------------------------
__global__ __launch_bounds__(256) void k_lam(
    const float* __restrict__ U, const float* __restrict__ sumw,
    const float* __restrict__ Wv, float* __restrict__ lam, float* __restrict__ st)
{
    const int b = blockIdx.y;
    const int e = blockIdx.x * 256 + threadIdx.x;   // 0..2047
    const int m = e >> 7;
    const int d = e & 127;
    const float* u = U + ((size_t)b * MID + m) * CTXD;
    float dot = 0.f;
    #pragma unroll 8
    for (int k = 0; k < CTXD; ++k)
        dot += u[k] * Wv[k * OUTD + d];
    float l = dot / sumw[b * MID + m];
    lam[((size_t)b * MID + m) * OUTD + d] = l;
    float s1 = l, s2 = l * l;
    #pragma unroll
    for (int off = 32; off > 0; off >>= 1) {
        s1 += __shfl_down(s1, off);
        s2 += __shfl_down(s2, off);
    }
    if ((threadIdx.x & 63) == 0) {
        atomicAdd(&st[m], s1);
        atomicAdd(&st[MID + m], s2);
    }
}

// ---------------------------------------------------------------------------
// Phase 3: slab of 64 feat rows. bn->LDS; feat->LDS coalesced; q=feat@Wq
// (Wq via s_load); qL->LDS; out = q@bn with b128 reads, float4 stores.
// ---------------------------------------------------------------------------
__global__ __launch_bounds__(256) void k_out(
    const float* __restrict__ feat, const float* __restrict__ Wq,
    const float* __restrict__ lam, const float* __restrict__ st,
    const float* __restrict__ gamma, const float* __restrict__ beta,
    float* __restrict__ out)
{
    __shared__ float fL[ROWS * LPAD];    // 33792 B
    __shared__ float qL[ROWS * 20];      // 5120 B (stride 20 = 5 float4)
    __shared__ float bnL[MID * LPAD];    // 8448 B
    const int b  = blockIdx.y;
    const int r0 = blockIdx.x * ROWS;
    const int t  = threadIdx.x;
    const int lane = t & 63;

    // ---- bn staging ----
    #pragma unroll
    for (int i = 0; i < 8; ++i) {
        int e = t + 256 * i;            // 0..2047
        int m = e >> 7, d = e & 127;
        float mean = st[m] * (1.f / (BATCH * OUTD));
        float var  = st[MID + m] * (1.f / (BATCH * OUTD)) - mean * mean;
        float inv  = rsqrtf(var + EPSV);
        bnL[m * LPAD + d] =
            (lam[((size_t)b * MID + m) * OUTD + d] - mean) * inv * gamma[m] + beta[m];
    }
    // ---- feat staging ----
    {
        const float4* g4 = (const float4*)(feat + ((size_t)b * NQ + r0) * FEAT);
        float4* f4p = (float4*)fL;
        #pragma unroll
        for (int i = 0; i < 8; ++i) {
            int idx = t + 256 * i;
            int row = idx >> 5;
            int c4  = idx & 31;
            f4p[row * (LPAD / 4) + c4] = g4[idx];
        }
    }
    __syncthreads();

    // ---- q phase ----
    {
        const int g = __builtin_amdgcn_readfirstlane(t >> 6);
        float q0 = 0.f, q1 = 0.f, q2 = 0.f, q3 = 0.f;
        const float4* fr = (const float4*)fL + lane * (LPAD / 4);
        const float* wqb = Wq + 4 * g;
        #pragma unroll 8
        for (int kq = 0; kq < 32; ++kq) {
            float4 c4 = fr[kq];
            const float* w0p = wqb + (4 * kq + 0) * MID;
            const float* w1p = wqb + (4 * kq + 1) * MID;
            const float* w2p = wqb + (4 * kq + 2) * MID;
            const float* w3p = wqb + (4 * kq + 3) * MID;
            q0 += c4.x * w0p[0]; q1 += c4.x * w0p[1]; q2 += c4.x * w0p[2]; q3 += c4.x * w0p[3];
            q0 += c4.y * w1p[0]; q1 += c4.y * w1p[1]; q2 += c4.y * w1p[2]; q3 += c4.y * w1p[3];
            q0 += c4.z * w2p[0]; q1 += c4.z * w2p[1]; q2 += c4.z * w2p[2]; q3 += c4.z * w2p[3];
            q0 += c4.w * w3p[0]; q1 += c4.w * w3p[1]; q2 += c4.w * w3p[2]; q3 += c4.w * w3p[3];
        }
        ((float4*)qL)[lane * 5 + g] = make_float4(q0, q1, q2, q3);
    }
    __syncthreads();

    // ---- out phase: thread = 4 rows x 8 cols ----
    {
        const int nblk = t >> 4;        // 0..15
        const int dq   = t & 15;        // 0..15, d-chunk = 8*dq
        const float4* qL4  = (const float4*)qL;
        const float4* bnL4 = (const float4*)bnL;
        float qv[4][16];
        #pragma unroll
        for (int rr = 0; rr < 4; ++rr) {
            #pragma unroll
            for (int mq = 0; mq < 4; ++mq) {
                float4 v = qL4[(4 * nblk + rr) * 5 + mq];
                qv[rr][4 * mq + 0] = v.x; qv[rr][4 * mq + 1] = v.y;
                qv[rr][4 * mq + 2] = v.z; qv[rr][4 * mq + 3] = v.w;
            }
        }
        float acc[4][8];
        #pragma unroll
        for (int rr = 0; rr < 4; ++rr)
            #pragma unroll
            for (int j = 0; j < 8; ++j) acc[rr][j] = 0.f;

        #pragma unroll
        for (int m = 0; m < 16; ++m) {
            float4 b0 = bnL4[m * (LPAD / 4) + 2 * dq];
            float4 b1 = bnL4[m * (LPAD / 4) + 2 * dq + 1];
            #pragma unroll
            for (int rr = 0; rr < 4; ++rr) {
                float qq = qv[rr][m];
                acc[rr][0] += qq * b0.x; acc[rr][1] += qq * b0.y;
                acc[rr][2] += qq * b0.z; acc[rr][3] += qq * b0.w;
                acc[rr][4] += qq * b1.x; acc[rr][5] += qq * b1.y;
                acc[rr][6] += qq * b1.z; acc[rr][7] += qq * b1.w;
            }
        }
        #pragma unroll
        for (int rr = 0; rr < 4; ++rr) {
            float4* op = (float4*)(out + ((size_t)b * NQ + r0 + 4 * nblk + rr) * OUTD + 8 * dq);
            op[0] = make_float4(acc[rr][0], acc[rr][1], acc[rr][2], acc[rr][3]);
            op[1] = make_float4(acc[rr][4], acc[rr][5], acc[rr][6], acc[rr][7]);
        }
    }
}

extern "C" void kernel_launch(void* const* d_in, const int* in_sizes, int n_in,
                              void* d_out, int out_size, void* d_ws, size_t ws_size,
                              hipStream_t stream)
{
    const float* feat  = (const float*)d_in[0];
    const float* ctx   = (const float*)d_in[1];
    const float* Wq    = (const float*)d_in[2];
    const float* Wk    = (const float*)d_in[3];
    const float* Wv    = (const float*)d_in[4];
    const float* gamma = (const float*)d_in[5];
    const float* beta  = (const float*)d_in[6];
    float* out = (float*)d_out;

    float* ws   = (float*)d_ws;
    float* U    = ws;            // 16384
    float* sumw = ws + 16384;    // 128
    float* st   = ws + 16512;    // 32
    float* lam  = ws + 16544;    // 16384

    hipMemsetAsync(d_ws, 0, 16544 * sizeof(float), stream);
    k_phase1<<<dim3(NK / ROWS, BATCH), 256, 0, stream>>>(ctx, Wk, U, sumw);
    k_lam<<<dim3(8, BATCH), 256, 0, stream>>>(U, sumw, Wv, lam, st);
    k_out<<<dim3(NQ / ROWS, BATCH), 256, 0, stream>>>(feat, Wq, lam, st, gamma, beta, out);
}

// Round 4
// 222.269 us; speedup vs baseline: 1.8344x; 1.8344x over previous
//
#include <hip/hip_runtime.h>
#include <cstddef>

#define BATCH 8
#define NQ 16384
#define NK 16384
#define FEAT 128
#define MID 16
#define CTXD 128
#define OUTD 128
#define EPSV 1e-5f

// ws layout (floats)
#define OFF_LAM 0         // [8][16][128] = 16384
#define OFF_ST  16384     // [2][16] BN sum/sumsq (zeroed)
#define OFF_SW  16448     // [8][16] sumw (atomic fallback, zeroed)
#define OFF_U   16576     // [8][16][128] (atomic fallback, zeroed)
#define OFF_S   32960     // [8][16][128] sumw partials  S[b][m][blk]
#define OFF_P   49408     // [8][128][16][128] U partials P[b][blk][m][d]
#define NEED_FLOATS (49408 + 8 * 128 * 16 * 128)

__device__ __forceinline__ float readlane_f(float v, int lane) {
    return __uint_as_float(__builtin_amdgcn_readlane(__float_as_uint(v), lane));
}

// ---------------------------------------------------------------------------
// Phase 1: block = 128 ctx rows (2 sub-slabs of 64). Wk staged in LDS (no
// s_load in inner loop!). key -> w=exp in regs; U partials accumulated in
// regs across sub-slabs; epilogue: partial stores (or atomics fallback).
// ---------------------------------------------------------------------------
template <bool PARTIALS>
__global__ __launch_bounds__(256) void k_phase1(
    const float* __restrict__ ctx, const float* __restrict__ Wk,
    float* __restrict__ P, float* __restrict__ S,
    float* __restrict__ U, float* __restrict__ sumwG)
{
    __shared__ float cL[64 * 132];     // 33792 B
    __shared__ float wkL[128 * 16];    // 8192 B
    const int b    = blockIdx.y;
    const int blk  = blockIdx.x;
    const int t    = threadIdx.x;
    const int lane = t & 63;
    const int g    = __builtin_amdgcn_readfirstlane(t >> 6);   // wave id 0..3

    #pragma unroll
    for (int i = 0; i < 8; ++i) wkL[t + 256 * i] = Wk[t + 256 * i];

    float a00 = 0.f, a01 = 0.f, a10 = 0.f, a11 = 0.f;
    float a20 = 0.f, a21 = 0.f, a30 = 0.f, a31 = 0.f;
    float sw0 = 0.f, sw1 = 0.f, sw2 = 0.f, sw3 = 0.f;
    const size_t rowbase = (size_t)b * NK + (size_t)blk * 128;

    for (int s = 0; s < 2; ++s) {
        __syncthreads();   // cL free (and wkL visible after first pass)
        {
            const float4* g4 = (const float4*)(ctx + (rowbase + 64 * s) * CTXD);
            float4* c4p = (float4*)cL;
            #pragma unroll
            for (int i = 0; i < 8; ++i) {
                int idx = t + 256 * i;
                c4p[(idx >> 5) * 33 + (idx & 31)] = g4[idx];
            }
        }
        __syncthreads();

        // ---- key: 512 FMA, all operands from LDS ----
        float k0 = 0.f, k1 = 0.f, k2 = 0.f, k3 = 0.f;
        {
            const float4* cr = (const float4*)cL + lane * 33;
            #pragma unroll 8
            for (int kq = 0; kq < 32; ++kq) {
                float4 c4  = cr[kq];
                float4 wr0 = *(const float4*)(wkL + (4 * kq + 0) * 16 + 4 * g);
                float4 wr1 = *(const float4*)(wkL + (4 * kq + 1) * 16 + 4 * g);
                float4 wr2 = *(const float4*)(wkL + (4 * kq + 2) * 16 + 4 * g);
                float4 wr3 = *(const float4*)(wkL + (4 * kq + 3) * 16 + 4 * g);
                k0 += c4.x * wr0.x + c4.y * wr1.x + c4.z * wr2.x + c4.w * wr3.x;
                k1 += c4.x * wr0.y + c4.y * wr1.y + c4.z * wr2.y + c4.w * wr3.y;
                k2 += c4.x * wr0.z + c4.y * wr1.z + c4.z * wr2.z + c4.w * wr3.z;
                k3 += c4.x * wr0.w + c4.y * wr1.w + c4.z * wr2.w + c4.w * wr3.w;
            }
        }
        float w0 = __expf(k0), w1 = __expf(k1), w2 = __expf(k2), w3 = __expf(k3);

        // ---- sumw all-reduce across wave ----
        {
            float s0 = w0, s1 = w1, s2 = w2, s3 = w3;
            #pragma unroll
            for (int off = 32; off > 0; off >>= 1) {
                s0 += __shfl_xor(s0, off); s1 += __shfl_xor(s1, off);
                s2 += __shfl_xor(s2, off); s3 += __shfl_xor(s3, off);
            }
            sw0 += s0; sw1 += s1; sw2 += s2; sw3 += s3;
        }

        // ---- U accumulate: wave g owns mids 4g..4g+3, lane owns 2 d-cols ----
        #pragma unroll 4
        for (int n = 0; n < 64; ++n) {
            float b0 = readlane_f(w0, n);
            float b1 = readlane_f(w1, n);
            float b2 = readlane_f(w2, n);
            float b3 = readlane_f(w3, n);
            float2 c2 = *(const float2*)(cL + n * 132 + 2 * lane);
            a00 += b0 * c2.x; a01 += b0 * c2.y;
            a10 += b1 * c2.x; a11 += b1 * c2.y;
            a20 += b2 * c2.x; a21 += b2 * c2.y;
            a30 += b3 * c2.x; a31 += b3 * c2.y;
        }
    }

    if (PARTIALS) {
        float2* p0 = (float2*)(P + (((size_t)b * 128 + blk) * 16 + 4 * g) * 128 + 2 * lane);
        p0[0]          = make_float2(a00, a01);
        p0[64]         = make_float2(a10, a11);   // +128 floats
        p0[128]        = make_float2(a20, a21);
        p0[192]        = make_float2(a30, a31);
        if (lane == 0) {
            S[((size_t)b * 16 + 4 * g + 0) * 128 + blk] = sw0;
            S[((size_t)b * 16 + 4 * g + 1) * 128 + blk] = sw1;
            S[((size_t)b * 16 + 4 * g + 2) * 128 + blk] = sw2;
            S[((size_t)b * 16 + 4 * g + 3) * 128 + blk] = sw3;
        }
    } else {
        float* u0 = U + ((size_t)b * 16 + 4 * g) * 128 + 2 * lane;
        atomicAdd(u0 + 0,   a00); atomicAdd(u0 + 1,   a01);
        atomicAdd(u0 + 128, a10); atomicAdd(u0 + 129, a11);
        atomicAdd(u0 + 256, a20); atomicAdd(u0 + 257, a21);
        atomicAdd(u0 + 384, a30); atomicAdd(u0 + 385, a31);
        if (lane == 0) {
            atomicAdd(&sumwG[b * 16 + 4 * g + 0], sw0);
            atomicAdd(&sumwG[b * 16 + 4 * g + 1], sw1);
            atomicAdd(&sumwG[b * 16 + 4 * g + 2], sw2);
            atomicAdd(&sumwG[b * 16 + 4 * g + 3], sw3);
        }
    }
}

// ---------------------------------------------------------------------------
// Phase 2 (fused reducer): block (m,b): reduce P -> U row, reduce S -> sumw,
// lam = U@Wv / sumw, BN-stat atomics (512 total).
// ---------------------------------------------------------------------------
template <bool PARTIALS>
__global__ __launch_bounds__(256) void k_lam(
    const float* __restrict__ P, const float* __restrict__ S,
    const float* __restrict__ U, const float* __restrict__ sumwG,
    const float* __restrict__ Wv, float* __restrict__ lam, float* __restrict__ st)
{
    const int m = blockIdx.x, b = blockIdx.y, t = threadIdx.x;
    __shared__ float uL[128];
    __shared__ float red[256];
    __shared__ float swL;
    const int d = t & 127, h = t >> 7;

    float acc = 0.f;
    if (PARTIALS) {
        const float* p = P + ((size_t)b * 128 * 16 + m) * 128 + d;
        for (int blk = h; blk < 128; blk += 2) acc += p[(size_t)blk * 2048];
    } else {
        if (h == 0) acc = U[((size_t)b * 16 + m) * 128 + d];
    }
    red[t] = acc;

    if (t < 64) {
        float s;
        if (PARTIALS) {
            const float* sp = S + ((size_t)b * 16 + m) * 128;
            s = sp[t] + sp[t + 64];
            #pragma unroll
            for (int off = 32; off > 0; off >>= 1) s += __shfl_xor(s, off);
        } else {
            s = sumwG[b * 16 + m];
        }
        if (t == 0) swL = s;
    }
    __syncthreads();
    if (t < 128) uL[t] = red[t] + red[t + 128];
    __syncthreads();

    float dot = 0.f;
    const float* wv = Wv + h * 64 * OUTD + d;
    #pragma unroll 8
    for (int k = 0; k < 64; ++k) dot += uL[h * 64 + k] * wv[k * OUTD];
    red[t] = dot;
    __syncthreads();
    if (t < 128) {
        float l = (red[t] + red[t + 128]) / swL;
        lam[((size_t)b * 16 + m) * 128 + t] = l;
        float s1 = l, s2 = l * l;
        #pragma unroll
        for (int off = 32; off > 0; off >>= 1) {
            s1 += __shfl_xor(s1, off);
            s2 += __shfl_xor(s2, off);
        }
        if ((t & 63) == 0) {
            atomicAdd(&st[m], s1);
            atomicAdd(&st[16 + m], s2);
        }
    }
}

// ---------------------------------------------------------------------------
// Phase 3: slab of 64 feat rows. Wq in LDS (no s_load in loop); bn in LDS;
// q -> qL aliased into dead fL space; out = q@bn, coalesced float4 stores.
// ---------------------------------------------------------------------------
__global__ __launch_bounds__(256) void k_out(
    const float* __restrict__ feat, const float* __restrict__ Wq,
    const float* __restrict__ lam, const float* __restrict__ st,
    const float* __restrict__ gamma, const float* __restrict__ beta,
    float* __restrict__ out)
{
    __shared__ float fL[64 * 132];     // 33792 B (aliased for qL after q phase)
    __shared__ float bnL[16 * 132];    // 8448 B
    __shared__ float wqL[128 * 16];    // 8192 B  -> 50432 B total, 3 blocks/CU
    const int b    = blockIdx.y;
    const int t    = threadIdx.x;
    const int lane = t & 63;
    const size_t r0 = (size_t)blockIdx.x * 64;

    #pragma unroll
    for (int i = 0; i < 8; ++i) wqL[t + 256 * i] = Wq[t + 256 * i];

    #pragma unroll
    for (int i = 0; i < 8; ++i) {
        int e = t + 256 * i;
        int m = e >> 7, d = e & 127;
        float mean = st[m] * (1.f / (BATCH * OUTD));
        float var  = st[16 + m] * (1.f / (BATCH * OUTD)) - mean * mean;
        bnL[m * 132 + d] =
            (lam[((size_t)b * 16 + m) * 128 + d] - mean) * rsqrtf(var + EPSV) * gamma[m] + beta[m];
    }
    {
        const float4* g4 = (const float4*)(feat + ((size_t)b * NQ + r0) * FEAT);
        float4* f4p = (float4*)fL;
        #pragma unroll
        for (int i = 0; i < 8; ++i) {
            int idx = t + 256 * i;
            f4p[(idx >> 5) * 33 + (idx & 31)] = g4[idx];
        }
    }
    __syncthreads();

    // ---- q phase ----
    float q0 = 0.f, q1 = 0.f, q2 = 0.f, q3 = 0.f;
    {
        const int g = __builtin_amdgcn_readfirstlane(t >> 6);
        const float4* fr = (const float4*)fL + lane * 33;
        #pragma unroll 8
        for (int kq = 0; kq < 32; ++kq) {
            float4 c4  = fr[kq];
            float4 wr0 = *(const float4*)(wqL + (4 * kq + 0) * 16 + 4 * g);
            float4 wr1 = *(const float4*)(wqL + (4 * kq + 1) * 16 + 4 * g);
            float4 wr2 = *(const float4*)(wqL + (4 * kq + 2) * 16 + 4 * g);
            float4 wr3 = *(const float4*)(wqL + (4 * kq + 3) * 16 + 4 * g);
            q0 += c4.x * wr0.x + c4.y * wr1.x + c4.z * wr2.x + c4.w * wr3.x;
            q1 += c4.x * wr0.y + c4.y * wr1.y + c4.z * wr2.y + c4.w * wr3.y;
            q2 += c4.x * wr0.z + c4.y * wr1.z + c4.z * wr2.z + c4.w * wr3.z;
            q3 += c4.x * wr0.w + c4.y * wr1.w + c4.z * wr2.w + c4.w * wr3.w;
        }
    }
    __syncthreads();   // all fL reads done
    {
        const int g = __builtin_amdgcn_readfirstlane(t >> 6);
        ((float4*)fL)[lane * 5 + g] = make_float4(q0, q1, q2, q3);  // qL stride 20 floats
    }
    __syncthreads();

    // ---- out phase: thread = 4 rows x 8 cols ----
    {
        const int nblk = t >> 4;        // 0..15
        const int dq   = t & 15;        // 0..15 -> d = 8*dq
        const float4* qL4  = (const float4*)fL;
        const float4* bnL4 = (const float4*)bnL;
        float qv[4][16];
        #pragma unroll
        for (int rr = 0; rr < 4; ++rr) {
            #pragma unroll
            for (int mq = 0; mq < 4; ++mq) {
                float4 v = qL4[(4 * nblk + rr) * 5 + mq];
                qv[rr][4 * mq + 0] = v.x; qv[rr][4 * mq + 1] = v.y;
                qv[rr][4 * mq + 2] = v.z; qv[rr][4 * mq + 3] = v.w;
            }
        }
        float accv[4][8];
        #pragma unroll
        for (int rr = 0; rr < 4; ++rr)
            #pragma unroll
            for (int j = 0; j < 8; ++j) accv[rr][j] = 0.f;

        #pragma unroll
        for (int m = 0; m < 16; ++m) {
            float4 b0 = bnL4[m * 33 + 2 * dq];
            float4 b1 = bnL4[m * 33 + 2 * dq + 1];
            #pragma unroll
            for (int rr = 0; rr < 4; ++rr) {
                float qq = qv[rr][m];
                accv[rr][0] += qq * b0.x; accv[rr][1] += qq * b0.y;
                accv[rr][2] += qq * b0.z; accv[rr][3] += qq * b0.w;
                accv[rr][4] += qq * b1.x; accv[rr][5] += qq * b1.y;
                accv[rr][6] += qq * b1.z; accv[rr][7] += qq * b1.w;
            }
        }
        #pragma unroll
        for (int rr = 0; rr < 4; ++rr) {
            float4* op = (float4*)(out + ((size_t)b * NQ + r0 + 4 * nblk + rr) * OUTD + 8 * dq);
            op[0] = make_float4(accv[rr][0], accv[rr][1], accv[rr][2], accv[rr][3]);
            op[1] = make_float4(accv[rr][4], accv[rr][5], accv[rr][6], accv[rr][7]);
        }
    }
}

extern "C" void kernel_launch(void* const* d_in, const int* in_sizes, int n_in,
                              void* d_out, int out_size, void* d_ws, size_t ws_size,
                              hipStream_t stream)
{
    const float* feat  = (const float*)d_in[0];
    const float* ctx   = (const float*)d_in[1];
    const float* Wq    = (const float*)d_in[2];
    const float* Wk    = (const float*)d_in[3];
    const float* Wv    = (const float*)d_in[4];
    const float* gamma = (const float*)d_in[5];
    const float* beta  = (const float*)d_in[6];
    float* out = (float*)d_out;

    float* ws    = (float*)d_ws;
    float* lam   = ws + OFF_LAM;
    float* st    = ws + OFF_ST;
    float* sumwG = ws + OFF_SW;
    float* U     = ws + OFF_U;
    float* S     = ws + OFF_S;
    float* P     = ws + OFF_P;

    const bool partials = ws_size >= (size_t)NEED_FLOATS * sizeof(float);

    if (partials) {
        hipMemsetAsync((char*)d_ws + OFF_ST * sizeof(float), 0, 64 * sizeof(float), stream);
        k_phase1<true><<<dim3(128, BATCH), 256, 0, stream>>>(ctx, Wk, P, S, U, sumwG);
        k_lam<true><<<dim3(MID, BATCH), 256, 0, stream>>>(P, S, U, sumwG, Wv, lam, st);
    } else {
        hipMemsetAsync((char*)d_ws + OFF_ST * sizeof(float), 0,
                       (OFF_U + 16384 - OFF_ST) * sizeof(float), stream);
        k_phase1<false><<<dim3(128, BATCH), 256, 0, stream>>>(ctx, Wk, P, S, U, sumwG);
        k_lam<false><<<dim3(MID, BATCH), 256, 0, stream>>>(P, S, U, sumwG, Wv, lam, st);
    }
    k_out<<<dim3(NQ / 64, BATCH), 256, 0, stream>>>(feat, Wq, lam, st, gamma, beta, out);
}